// Round 10
// baseline (365.937 us; speedup 1.0000x reference)
//
#include <hip/hip_runtime.h>
#include <math.h>

#define HEADS 2
#define CH    128          // per-head channels
#define HC    256          // HEADS*CH
#define NEG   0.2f         // leaky_relu slope

typedef __attribute__((ext_vector_type(8))) short  bfrag8;   // 8 bf16 (4 VGPR)
typedef __attribute__((ext_vector_type(4))) float  f32x4;    // MFMA accumulator

// round-to-nearest-even fp32 -> bf16 (as raw u16)
__device__ inline unsigned short f2bf_rne(float x) {
    unsigned u = __float_as_uint(x);
    u += 0x7fffu + ((u >> 16) & 1u);
    return (unsigned short)(u >> 16);
}
// 2-term split: x ~= hi + lo (both bf16); residual ~2^-16 relative
__device__ inline void split2(float x, unsigned short& hi, unsigned short& lo) {
    unsigned u = __float_as_uint(x);
    unsigned r = u + 0x7fffu + ((u >> 16) & 1u);
    unsigned short h = (unsigned short)(r >> 16);
    float hf = __uint_as_float((unsigned)h << 16);
    hi = h;
    lo = f2bf_rne(x - hf);
}

// ---------------------------------------------------------------------------
// W pre-split: W[K][HC] fp32 -> Wthi/Wtlo[HC][K] bf16 (k-contiguous, transposed)
// ---------------------------------------------------------------------------
__global__ __launch_bounds__(256)
void wsplit_kernel(const float* __restrict__ W, unsigned short* __restrict__ Whi,
                   unsigned short* __restrict__ Wlo, int K) {
    const int idx = blockIdx.x * 256 + threadIdx.x;
    if (idx >= K * HC) return;
    const int k = idx >> 8;          // HC == 256
    const int n = idx & 255;
    unsigned short h, l;
    split2(W[idx], h, l);
    Whi[(size_t)n * K + k] = h;
    Wlo[(size_t)n * K + k] = l;
}

// ---------------------------------------------------------------------------
// A pre-split (for layer-1 input x): fp32 [N*K] -> hi/lo bf16 planes
// ---------------------------------------------------------------------------
__global__ __launch_bounds__(256)
void asplit_kernel(const float* __restrict__ A, unsigned short* __restrict__ Ahi,
                   unsigned short* __restrict__ Alo, int total4) {
    const int idx = blockIdx.x * 256 + threadIdx.x;
    if (idx >= total4) return;
    const float4 v = *reinterpret_cast<const float4*>(&A[idx * 4]);
    ushort4 hv, lv;
    split2(v.x, hv.x, lv.x);
    split2(v.y, hv.y, lv.y);
    split2(v.z, hv.z, lv.z);
    split2(v.w, hv.w, lv.w);
    *reinterpret_cast<ushort4*>(&Ahi[idx * 4]) = hv;
    *reinterpret_cast<ushort4*>(&Alo[idx * 4]) = lv;
}

// ---------------------------------------------------------------------------
// Fused GEMM + alpha + bf16 pack. A is pre-split hi/lo bf16 planes [M][K].
//   acc = A @ W (3-pass split MFMA, fp32 accumulate)
//   xWb[row] = bf16(acc);  as/ad[row, head=blockIdx.y] = fp32 alpha dots
// tile 128x128, BK=32, 4 waves (2x2); block y covers exactly one head.
// ---------------------------------------------------------------------------
__global__ __launch_bounds__(256)
void gemm_fused_kernel(const unsigned short* __restrict__ Ahi,
                       const unsigned short* __restrict__ Alo,
                       const unsigned short* __restrict__ Wthi,
                       const unsigned short* __restrict__ Wtlo,
                       const float* __restrict__ a_src,
                       const float* __restrict__ a_dst,
                       unsigned short* __restrict__ xWb,
                       float* __restrict__ as_out, float* __restrict__ ad_out,
                       int M, int K) {
    __shared__ unsigned short Ah[128][40];
    __shared__ unsigned short Al[128][40];
    __shared__ unsigned short Bh[128][40];
    __shared__ unsigned short Bl[128][40];

    const int t    = threadIdx.x;
    const int row0 = blockIdx.x * 128;
    const int col0 = blockIdx.y * 128;   // == head * 128
    const int lane = t & 63;
    const int wid  = t >> 6;
    const int wr   = wid >> 1;
    const int wc   = wid & 1;

    f32x4 acc[4][4] = {};

    const int ar  = t >> 2;          // A staging: base row 0..63
    const int ac8 = (t & 3) * 8;     // A staging: k offset 0,8,16,24
    const int bcol   = t >> 1;       // B staging: col 0..127
    const int bplane = t & 1;        // 0 = hi, 1 = lo

    for (int kk = 0; kk < K; kk += 32) {
        // ---- stage A (128 x 32, hi+lo planes, plain copies) ----
        #pragma unroll
        for (int rep = 0; rep < 2; ++rep) {
            const int row = ar + rep * 64;
            const int gr  = row0 + row;
            bfrag8 vh = {0, 0, 0, 0, 0, 0, 0, 0};
            bfrag8 vl = {0, 0, 0, 0, 0, 0, 0, 0};
            if (gr < M) {
                vh = *reinterpret_cast<const bfrag8*>(&Ahi[(size_t)gr * K + kk + ac8]);
                vl = *reinterpret_cast<const bfrag8*>(&Alo[(size_t)gr * K + kk + ac8]);
            }
            *reinterpret_cast<bfrag8*>(&Ah[row][ac8]) = vh;
            *reinterpret_cast<bfrag8*>(&Al[row][ac8]) = vl;
        }
        // ---- stage B (128 cols x 32 k, pre-split planes) ----
        {
            const unsigned short* srcp =
                (bplane ? Wtlo : Wthi) + (size_t)(col0 + bcol) * K + kk;
            unsigned short (*dst)[40] = bplane ? Bl : Bh;
            #pragma unroll
            for (int q = 0; q < 4; ++q) {
                bfrag8 v = *reinterpret_cast<const bfrag8*>(srcp + q * 8);
                *reinterpret_cast<bfrag8*>(&dst[bcol][q * 8]) = v;
            }
        }
        __syncthreads();

        bfrag8 ah[4], al[4], bh[4], bl[4];
        const int ko = (lane >> 4) * 8;
        #pragma unroll
        for (int m = 0; m < 4; ++m) {
            const int row = wr * 64 + m * 16 + (lane & 15);
            ah[m] = *reinterpret_cast<const bfrag8*>(&Ah[row][ko]);
            al[m] = *reinterpret_cast<const bfrag8*>(&Al[row][ko]);
        }
        #pragma unroll
        for (int n = 0; n < 4; ++n) {
            const int col = wc * 64 + n * 16 + (lane & 15);
            bh[n] = *reinterpret_cast<const bfrag8*>(&Bh[col][ko]);
            bl[n] = *reinterpret_cast<const bfrag8*>(&Bl[col][ko]);
        }

        #pragma unroll
        for (int m = 0; m < 4; ++m)
            #pragma unroll
            for (int n = 0; n < 4; ++n) {
                acc[m][n] = __builtin_amdgcn_mfma_f32_16x16x32_bf16(al[m], bh[n], acc[m][n], 0, 0, 0);
                acc[m][n] = __builtin_amdgcn_mfma_f32_16x16x32_bf16(ah[m], bl[n], acc[m][n], 0, 0, 0);
                acc[m][n] = __builtin_amdgcn_mfma_f32_16x16x32_bf16(ah[m], bh[n], acc[m][n], 0, 0, 0);
            }
        __syncthreads();
    }

    // ---- fused epilogue: alpha dots (exact fp32) + bf16 message store ----
    __shared__ float s_lds[2][128];
    __shared__ float d_lds[2][128];

    float asv[4], adv[4];
    #pragma unroll
    for (int n = 0; n < 4; ++n) {
        const int gc = col0 + wc * 64 + n * 16 + (lane & 15);
        asv[n] = a_src[gc];
        adv[n] = a_dst[gc];
    }

    #pragma unroll
    for (int m = 0; m < 4; ++m) {
        #pragma unroll
        for (int reg = 0; reg < 4; ++reg) {
            const int row = wr * 64 + m * 16 + (lane >> 4) * 4 + reg;
            const int gr  = row0 + row;
            float ps = acc[m][0][reg] * asv[0] + acc[m][1][reg] * asv[1] +
                       acc[m][2][reg] * asv[2] + acc[m][3][reg] * asv[3];
            float pd = acc[m][0][reg] * adv[0] + acc[m][1][reg] * adv[1] +
                       acc[m][2][reg] * adv[2] + acc[m][3][reg] * adv[3];
            #pragma unroll
            for (int msk = 1; msk <= 8; msk <<= 1) {
                ps += __shfl_xor(ps, msk);
                pd += __shfl_xor(pd, msk);
            }
            if ((lane & 15) == 0) {
                s_lds[wc][row] = ps;
                d_lds[wc][row] = pd;
            }
            if (gr < M) {
                unsigned short* rp = &xWb[(size_t)gr * HC + col0];
                #pragma unroll
                for (int n = 0; n < 4; ++n)
                    rp[wc * 64 + n * 16 + (lane & 15)] = f2bf_rne(acc[m][n][reg]);
            }
        }
    }
    __syncthreads();
    if (t < 128) {
        const int gr = row0 + t;
        if (gr < M) {
            as_out[gr * 2 + blockIdx.y] = s_lds[0][t] + s_lds[1][t];
            ad_out[gr * 2 + blockIdx.y] = d_lds[0][t] + d_lds[1][t];
        }
    }
}

// ---------------------------------------------------------------------------
// CSR build: histogram -> 2-level exclusive scan -> scatter (by destination)
// ---------------------------------------------------------------------------
__global__ __launch_bounds__(256)
void hist_kernel(const int* __restrict__ dst, int* __restrict__ counts, int E) {
    const int e = blockIdx.x * 256 + threadIdx.x;
    if (e < E) atomicAdd(&counts[dst[e]], 1);
}

__global__ __launch_bounds__(256)
void scan_local_kernel(int* __restrict__ data, int* __restrict__ chunk_sum, int N) {
    __shared__ int s[256];
    const int t   = threadIdx.x;
    const int idx = blockIdx.x * 256 + t;
    const int v   = (idx < N) ? data[idx] : 0;
    s[t] = v;
    __syncthreads();
    #pragma unroll
    for (int off = 1; off < 256; off <<= 1) {
        int x = (t >= off) ? s[t - off] : 0;
        __syncthreads();
        s[t] += x;
        __syncthreads();
    }
    if (idx < N) data[idx] = s[t] - v;        // exclusive
    if (t == 255) chunk_sum[blockIdx.x] = s[255];
}

__global__ __launch_bounds__(256)
void scan_chunks_kernel(int* __restrict__ chunk, int nb) {
    __shared__ int s[256];
    const int t = threadIdx.x;
    const int v = (t < nb) ? chunk[t] : 0;
    s[t] = v;
    __syncthreads();
    #pragma unroll
    for (int off = 1; off < 256; off <<= 1) {
        int x = (t >= off) ? s[t - off] : 0;
        __syncthreads();
        s[t] += x;
        __syncthreads();
    }
    if (t < nb) chunk[t] = s[t] - v;
}

__global__ __launch_bounds__(256)
void add_offsets_kernel(const int* __restrict__ excl, const int* __restrict__ chunk_excl,
                        int* __restrict__ row_ptr, int* __restrict__ cursor,
                        int N, int E) {
    const int idx = blockIdx.x * 256 + threadIdx.x;
    if (idx < N) {
        const int rp = excl[idx] + chunk_excl[idx >> 8];
        row_ptr[idx] = rp;
        cursor[idx]  = rp;
    }
    if (idx == 0) row_ptr[N] = E;
}

__global__ __launch_bounds__(256)
void scatter_kernel(const int* __restrict__ src, const int* __restrict__ dst,
                    int* __restrict__ cursor, int* __restrict__ col_idx, int E) {
    const int e = blockIdx.x * 256 + threadIdx.x;
    if (e < E) {
        const int pos = atomicAdd(&cursor[dst[e]], 1);
        col_idx[pos] = src[e];
    }
}

// ---------------------------------------------------------------------------
// gather aggregation + fused epilogue: one wave per target node.
// bf16 messages; 4 edge streams (16 lanes each, 16 ch/lane, 32 B/lane loads).
// mode 1: ELU + split -> outhi/outlo (next-layer GEMM input planes)
// mode 0: fp32 -> outf
// ---------------------------------------------------------------------------
__global__ __launch_bounds__(256)
void agg_kernel(const int* __restrict__ row_ptr, const int* __restrict__ col_idx,
                const unsigned short* __restrict__ xWb,
                const float* __restrict__ as_, const float* __restrict__ ad_,
                const float* __restrict__ bias, float* __restrict__ outf,
                unsigned short* __restrict__ outhi, unsigned short* __restrict__ outlo,
                int N, int mode) {
    const int wv   = (blockIdx.x * 256 + threadIdx.x) >> 6;
    const int lane = threadIdx.x & 63;
    if (wv >= N) return;
    const int i      = wv;
    const int stream = lane >> 4;        // 4 edge streams
    const int sl     = lane & 15;
    const int hh     = sl >> 3;          // sl 0-7 head0, 8-15 head1
    const int cb     = sl * 16;          // 16-channel block base
    const float adi  = ad_[i * 2 + hh];

    float acc[16] = {};
    float dn = 0.f;

    const int beg = row_ptr[i];
    const int end = row_ptr[i + 1];

    int k = beg + stream;
    int j = (k < end) ? col_idx[k] : 0;
    float asj = as_[j * 2 + hh];
    for (; k < end; k += 4) {
        const int kn = k + 4;
        const int jn = (kn < end) ? col_idx[kn] : 0;     // prefetch idx
        const float asn = as_[jn * 2 + hh];              // prefetch alpha_src
        float e = asj + adi;
        e = e > 0.f ? e : NEG * e;
        const float w = expf(e);
        const uint4 q0 = *reinterpret_cast<const uint4*>(&xWb[(size_t)j * HC + cb]);
        const uint4 q1 = *reinterpret_cast<const uint4*>(&xWb[(size_t)j * HC + cb + 8]);
        const unsigned qq[8] = {q0.x, q0.y, q0.z, q0.w, q1.x, q1.y, q1.z, q1.w};
        #pragma unroll
        for (int r = 0; r < 8; ++r) {
            const float flo = __uint_as_float(qq[r] << 16);
            const float fhi = __uint_as_float(qq[r] & 0xffff0000u);
            acc[r * 2 + 0] = fmaf(w, flo, acc[r * 2 + 0]);
            acc[r * 2 + 1] = fmaf(w, fhi, acc[r * 2 + 1]);
        }
        dn += w;
        j = jn; asj = asn;
    }

    // merge the four edge streams
    #pragma unroll
    for (int r = 0; r < 16; ++r) {
        acc[r] += __shfl_xor(acc[r], 16);
        acc[r] += __shfl_xor(acc[r], 32);
    }
    dn += __shfl_xor(dn, 16);
    dn += __shfl_xor(dn, 32);

    if (lane < 16) {
        // self loop (bf16 row — same error class as neighbor messages)
        float e = as_[i * 2 + hh] + adi;
        e = e > 0.f ? e : NEG * e;
        const float ws = expf(e);
        const uint4 q0 = *reinterpret_cast<const uint4*>(&xWb[(size_t)i * HC + cb]);
        const uint4 q1 = *reinterpret_cast<const uint4*>(&xWb[(size_t)i * HC + cb + 8]);
        const unsigned qq[8] = {q0.x, q0.y, q0.z, q0.w, q1.x, q1.y, q1.z, q1.w};
        #pragma unroll
        for (int r = 0; r < 8; ++r) {
            const float flo = __uint_as_float(qq[r] << 16);
            const float fhi = __uint_as_float(qq[r] & 0xffff0000u);
            acc[r * 2 + 0] = fmaf(ws, flo, acc[r * 2 + 0]);
            acc[r * 2 + 1] = fmaf(ws, fhi, acc[r * 2 + 1]);
        }
        dn += ws;

        const float inv = 1.f / dn;
        float o[16];
        #pragma unroll
        for (int r = 0; r < 4; ++r) {
            const float4 b4 = *reinterpret_cast<const float4*>(&bias[cb + r * 4]);
            o[r * 4 + 0] = acc[r * 4 + 0] * inv + b4.x;
            o[r * 4 + 1] = acc[r * 4 + 1] * inv + b4.y;
            o[r * 4 + 2] = acc[r * 4 + 2] * inv + b4.z;
            o[r * 4 + 3] = acc[r * 4 + 3] * inv + b4.w;
        }
        if (mode) {
            // ELU then 2-term split for next layer's GEMM input
            #pragma unroll
            for (int r = 0; r < 16; ++r) o[r] = o[r] > 0.f ? o[r] : expm1f(o[r]);
            #pragma unroll
            for (int r = 0; r < 4; ++r) {
                ushort4 hv, lv;
                split2(o[r * 4 + 0], hv.x, lv.x);
                split2(o[r * 4 + 1], hv.y, lv.y);
                split2(o[r * 4 + 2], hv.z, lv.z);
                split2(o[r * 4 + 3], hv.w, lv.w);
                *reinterpret_cast<ushort4*>(&outhi[(size_t)i * HC + cb + r * 4]) = hv;
                *reinterpret_cast<ushort4*>(&outlo[(size_t)i * HC + cb + r * 4]) = lv;
            }
        } else {
            #pragma unroll
            for (int r = 0; r < 4; ++r)
                *reinterpret_cast<float4*>(&outf[(size_t)i * HC + cb + r * 4]) =
                    make_float4(o[r * 4 + 0], o[r * 4 + 1], o[r * 4 + 2], o[r * 4 + 3]);
        }
    }
}

// ---------------------------------------------------------------------------
extern "C" void kernel_launch(void* const* d_in, const int* in_sizes, int n_in,
                              void* d_out, int out_size, void* d_ws, size_t ws_size,
                              hipStream_t stream) {
    const float* x      = (const float*)d_in[0];
    const int*   ei     = (const int*)d_in[1];
    const float* W1     = (const float*)d_in[2];
    const float* a_src1 = (const float*)d_in[3];
    const float* a_dst1 = (const float*)d_in[4];
    const float* b1     = (const float*)d_in[5];
    const float* W2     = (const float*)d_in[6];
    const float* a_src2 = (const float*)d_in[7];
    const float* a_dst2 = (const float*)d_in[8];
    const float* b2     = (const float*)d_in[9];
    float* out = (float*)d_out;

    const int Nn = in_sizes[0] / 128;   // 50000 nodes
    const int E  = in_sizes[1] / 2;     // 800000 edges
    const int K1 = in_sizes[2] / HC;    // 128
    const int* src = ei;
    const int* dst = ei + E;

    // workspace layout
    float* as_b  = (float*)d_ws;                  // Nn*2
    float* ad_b  = as_b + (size_t)Nn * 2;         // Nn*2
    int*   tmp   = (int*)(ad_b + (size_t)Nn * 2); // Nn  (counts -> excl scan)
    int*   chunk = tmp + Nn;                      // 256
    int*   rowp  = chunk + 256;                   // Nn+1
    int*   curs  = rowp + (Nn + 1);               // Nn
    int*   colx  = curs + Nn;                     // E
    unsigned short* wt1hi = (unsigned short*)(colx + E);   // HC*K1
    unsigned short* wt1lo = wt1hi + (size_t)HC * K1;
    unsigned short* wt2hi = wt1lo + (size_t)HC * K1;       // HC*HC
    unsigned short* wt2lo = wt2hi + (size_t)HC * HC;
    unsigned short* xWb   = wt2lo + (size_t)HC * HC;       // Nn*HC bf16 messages
    unsigned short* xhi   = xWb + (size_t)Nn * HC;         // Nn*K1 (x planes)
    unsigned short* xlo   = xhi + (size_t)Nn * K1;
    unsigned short* hhi   = xlo + (size_t)Nn * K1;         // Nn*HC (h planes)
    unsigned short* hlo   = hhi + (size_t)Nn * HC;

    const int nb = (Nn + 255) / 256;

    // ---- pre-splits ----
    wsplit_kernel<<<(K1 * HC + 255) / 256, 256, 0, stream>>>(W1, wt1hi, wt1lo, K1);
    wsplit_kernel<<<(HC * HC + 255) / 256, 256, 0, stream>>>(W2, wt2hi, wt2lo, HC);
    asplit_kernel<<<(Nn * K1 / 4 + 255) / 256, 256, 0, stream>>>(x, xhi, xlo, Nn * K1 / 4);

    // ---- CSR build (shared by both layers) ----
    hipMemsetAsync(tmp, 0, (size_t)Nn * sizeof(int), stream);
    hist_kernel<<<(E + 255) / 256, 256, 0, stream>>>(dst, tmp, E);
    scan_local_kernel<<<nb, 256, 0, stream>>>(tmp, chunk, Nn);
    scan_chunks_kernel<<<1, 256, 0, stream>>>(chunk, nb);
    add_offsets_kernel<<<nb, 256, 0, stream>>>(tmp, chunk, rowp, curs, Nn, E);
    scatter_kernel<<<(E + 255) / 256, 256, 0, stream>>>(src, dst, curs, colx, E);

    const dim3 ggrid((Nn + 127) / 128, HC / 128);
    const int  agrid = (Nn + 3) / 4;   // one wave per node

    // ---- layer 1 ----
    gemm_fused_kernel<<<ggrid, 256, 0, stream>>>(xhi, xlo, wt1hi, wt1lo, a_src1, a_dst1,
                                                 xWb, as_b, ad_b, Nn, K1);
    agg_kernel<<<agrid, 256, 0, stream>>>(rowp, colx, xWb, as_b, ad_b, b1,
                                          (float*)nullptr, hhi, hlo, Nn, 1);

    // ---- layer 2 ----
    gemm_fused_kernel<<<ggrid, 256, 0, stream>>>(hhi, hlo, wt2hi, wt2lo, a_src2, a_dst2,
                                                 xWb, as_b, ad_b, Nn, HC);
    agg_kernel<<<agrid, 256, 0, stream>>>(rowp, colx, xWb, as_b, ad_b, b2,
                                          out, (unsigned short*)nullptr,
                                          (unsigned short*)nullptr, Nn, 0);
}

// Round 11
// 335.490 us; speedup vs baseline: 1.0908x; 1.0908x over previous
//
#include <hip/hip_runtime.h>
#include <math.h>

#define HEADS 2
#define CH    128          // per-head channels
#define HC    256          // HEADS*CH
#define NEG   0.2f         // leaky_relu slope

typedef __attribute__((ext_vector_type(8))) short  bfrag8;   // 8 bf16 (4 VGPR)
typedef __attribute__((ext_vector_type(4))) float  f32x4;    // MFMA accumulator

// round-to-nearest-even fp32 -> bf16 (as raw u16)
__device__ inline unsigned short f2bf_rne(float x) {
    unsigned u = __float_as_uint(x);
    u += 0x7fffu + ((u >> 16) & 1u);
    return (unsigned short)(u >> 16);
}

// ---------------------------------------------------------------------------
// W cast+transpose: W[K][HC] fp32 -> Wt[HC][K] bf16 (k-contiguous)
// ---------------------------------------------------------------------------
__global__ __launch_bounds__(256)
void wcast_kernel(const float* __restrict__ W, unsigned short* __restrict__ Wt, int K) {
    const int idx = blockIdx.x * 256 + threadIdx.x;
    if (idx >= K * HC) return;
    const int k = idx >> 8;          // HC == 256
    const int n = idx & 255;
    Wt[(size_t)n * K + k] = f2bf_rne(W[idx]);
}

// ---------------------------------------------------------------------------
// va[k][4] = {src_h0, src_h1, dst_h0, dst_h1} = dot(W[k, head-slice], a_vec)
// one wave per k; lanes 0-31 cover head0 cols 0..127, lanes 32-63 head1.
// ---------------------------------------------------------------------------
__global__ __launch_bounds__(256)
void va_kernel(const float* __restrict__ W, const float* __restrict__ a_src,
               const float* __restrict__ a_dst, float* __restrict__ va, int K) {
    const int k    = (blockIdx.x * 256 + threadIdx.x) >> 6;
    const int lane = threadIdx.x & 63;
    if (k >= K) return;
    const int c0 = lane * 4;
    const float4 w4 = *reinterpret_cast<const float4*>(&W[(size_t)k * HC + c0]);
    const float4 s4 = *reinterpret_cast<const float4*>(&a_src[c0]);
    const float4 d4 = *reinterpret_cast<const float4*>(&a_dst[c0]);
    float ps = w4.x * s4.x + w4.y * s4.y + w4.z * s4.z + w4.w * s4.w;
    float pd = w4.x * d4.x + w4.y * d4.y + w4.z * d4.z + w4.w * d4.w;
    #pragma unroll
    for (int m = 1; m <= 16; m <<= 1) {
        ps += __shfl_xor(ps, m);
        pd += __shfl_xor(pd, m);
    }
    if (lane == 0)  { va[k * 4 + 0] = ps; va[k * 4 + 2] = pd; }
    if (lane == 32) { va[k * 4 + 1] = ps; va[k * 4 + 3] = pd; }
}

// ---------------------------------------------------------------------------
// xprep: per node — bf16 cast of x row + exact fp32 logits via va1.
// one wave per node; K == 128 (2 fp32 per lane).
// ---------------------------------------------------------------------------
__global__ __launch_bounds__(256)
void xprep_kernel(const float* __restrict__ x, const float* __restrict__ va,
                  unsigned short* __restrict__ xb, float* __restrict__ as_out,
                  float* __restrict__ ad_out, int N, int K) {
    const int i    = (blockIdx.x * 256 + threadIdx.x) >> 6;
    const int lane = threadIdx.x & 63;
    if (i >= N) return;
    const float2 v = reinterpret_cast<const float2*>(&x[(size_t)i * K])[lane];
    ushort2 bv; bv.x = f2bf_rne(v.x); bv.y = f2bf_rne(v.y);
    reinterpret_cast<ushort2*>(&xb[(size_t)i * K])[lane] = bv;

    const float4 a0 = reinterpret_cast<const float4*>(va)[lane * 2 + 0];
    const float4 a1 = reinterpret_cast<const float4*>(va)[lane * 2 + 1];
    float p0 = v.x * a0.x + v.y * a1.x;   // src h0
    float p1 = v.x * a0.y + v.y * a1.y;   // src h1
    float p2 = v.x * a0.z + v.y * a1.z;   // dst h0
    float p3 = v.x * a0.w + v.y * a1.w;   // dst h1
    #pragma unroll
    for (int m = 1; m <= 32; m <<= 1) {
        p0 += __shfl_xor(p0, m);
        p1 += __shfl_xor(p1, m);
        p2 += __shfl_xor(p2, m);
        p3 += __shfl_xor(p3, m);
    }
    if (lane == 0) {
        as_out[i * 2 + 0] = p0; as_out[i * 2 + 1] = p1;
        ad_out[i * 2 + 0] = p2; ad_out[i * 2 + 1] = p3;
    }
}

// ---------------------------------------------------------------------------
// Single-pass bf16 message GEMM: xWb[M,HC] = bf16( Ab[M,K] @ Wt^T )
// tile 128x128, BK=32, 4 waves (2x2), 16 MFMA/k-step. Logits handled elsewhere.
// ---------------------------------------------------------------------------
__global__ __launch_bounds__(256)
void gemm_msg_kernel(const unsigned short* __restrict__ Ab,
                     const unsigned short* __restrict__ Wt,
                     unsigned short* __restrict__ xWb, int M, int K) {
    __shared__ unsigned short Ah[128][40];
    __shared__ unsigned short Bh[128][40];

    const int t    = threadIdx.x;
    const int row0 = blockIdx.x * 128;
    const int col0 = blockIdx.y * 128;
    const int lane = t & 63;
    const int wid  = t >> 6;
    const int wr   = wid >> 1;
    const int wc   = wid & 1;

    f32x4 acc[4][4] = {};

    const int arow = t & 127;        // staging row / col
    const int aseg = (t >> 7) * 16;  // k segment 0 or 16

    for (int kk = 0; kk < K; kk += 32) {
        {
            const int gr = row0 + arow;
            bfrag8 v0 = {0,0,0,0,0,0,0,0}, v1 = {0,0,0,0,0,0,0,0};
            if (gr < M) {
                v0 = *reinterpret_cast<const bfrag8*>(&Ab[(size_t)gr * K + kk + aseg]);
                v1 = *reinterpret_cast<const bfrag8*>(&Ab[(size_t)gr * K + kk + aseg + 8]);
            }
            *reinterpret_cast<bfrag8*>(&Ah[arow][aseg])     = v0;
            *reinterpret_cast<bfrag8*>(&Ah[arow][aseg + 8]) = v1;
            const bfrag8 w0 = *reinterpret_cast<const bfrag8*>(
                &Wt[(size_t)(col0 + arow) * K + kk + aseg]);
            const bfrag8 w1 = *reinterpret_cast<const bfrag8*>(
                &Wt[(size_t)(col0 + arow) * K + kk + aseg + 8]);
            *reinterpret_cast<bfrag8*>(&Bh[arow][aseg])     = w0;
            *reinterpret_cast<bfrag8*>(&Bh[arow][aseg + 8]) = w1;
        }
        __syncthreads();

        bfrag8 ah[4], bh[4];
        const int ko = (lane >> 4) * 8;
        #pragma unroll
        for (int m = 0; m < 4; ++m)
            ah[m] = *reinterpret_cast<const bfrag8*>(&Ah[wr * 64 + m * 16 + (lane & 15)][ko]);
        #pragma unroll
        for (int n = 0; n < 4; ++n)
            bh[n] = *reinterpret_cast<const bfrag8*>(&Bh[wc * 64 + n * 16 + (lane & 15)][ko]);

        #pragma unroll
        for (int m = 0; m < 4; ++m)
            #pragma unroll
            for (int n = 0; n < 4; ++n)
                acc[m][n] = __builtin_amdgcn_mfma_f32_16x16x32_bf16(ah[m], bh[n], acc[m][n], 0, 0, 0);
        __syncthreads();
    }

    // epilogue: bf16 stores (C/D layout col=lane&15, row=(lane>>4)*4+reg)
    #pragma unroll
    for (int m = 0; m < 4; ++m) {
        #pragma unroll
        for (int reg = 0; reg < 4; ++reg) {
            const int gr = row0 + wr * 64 + m * 16 + (lane >> 4) * 4 + reg;
            if (gr < M) {
                unsigned short* rp = &xWb[(size_t)gr * HC + col0];
                #pragma unroll
                for (int n = 0; n < 4; ++n)
                    rp[wc * 64 + n * 16 + (lane & 15)] = f2bf_rne(acc[m][n][reg]);
            }
        }
    }
}

// ---------------------------------------------------------------------------
// CSR build: histogram -> 2-level exclusive scan -> scatter (by destination)
// ---------------------------------------------------------------------------
__global__ __launch_bounds__(256)
void hist_kernel(const int* __restrict__ dst, int* __restrict__ counts, int E) {
    const int e = blockIdx.x * 256 + threadIdx.x;
    if (e < E) atomicAdd(&counts[dst[e]], 1);
}

__global__ __launch_bounds__(256)
void scan_local_kernel(int* __restrict__ data, int* __restrict__ chunk_sum, int N) {
    __shared__ int s[256];
    const int t   = threadIdx.x;
    const int idx = blockIdx.x * 256 + t;
    const int v   = (idx < N) ? data[idx] : 0;
    s[t] = v;
    __syncthreads();
    #pragma unroll
    for (int off = 1; off < 256; off <<= 1) {
        int x = (t >= off) ? s[t - off] : 0;
        __syncthreads();
        s[t] += x;
        __syncthreads();
    }
    if (idx < N) data[idx] = s[t] - v;        // exclusive
    if (t == 255) chunk_sum[blockIdx.x] = s[255];
}

__global__ __launch_bounds__(256)
void scan_chunks_kernel(int* __restrict__ chunk, int nb) {
    __shared__ int s[256];
    const int t = threadIdx.x;
    const int v = (t < nb) ? chunk[t] : 0;
    s[t] = v;
    __syncthreads();
    #pragma unroll
    for (int off = 1; off < 256; off <<= 1) {
        int x = (t >= off) ? s[t - off] : 0;
        __syncthreads();
        s[t] += x;
        __syncthreads();
    }
    if (t < nb) chunk[t] = s[t] - v;
}

__global__ __launch_bounds__(256)
void add_offsets_kernel(const int* __restrict__ excl, const int* __restrict__ chunk_excl,
                        int* __restrict__ row_ptr, int* __restrict__ cursor,
                        int N, int E) {
    const int idx = blockIdx.x * 256 + threadIdx.x;
    if (idx < N) {
        const int rp = excl[idx] + chunk_excl[idx >> 8];
        row_ptr[idx] = rp;
        cursor[idx]  = rp;
    }
    if (idx == 0) row_ptr[N] = E;
}

__global__ __launch_bounds__(256)
void scatter_kernel(const int* __restrict__ src, const int* __restrict__ dst,
                    int* __restrict__ cursor, int* __restrict__ col_idx, int E) {
    const int e = blockIdx.x * 256 + threadIdx.x;
    if (e < E) {
        const int pos = atomicAdd(&cursor[dst[e]], 1);
        col_idx[pos] = src[e];
    }
}

// ---------------------------------------------------------------------------
// gather aggregation + fused epilogue: one wave per target node.
// bf16 messages; 2 edge streams (lanes 0-31 / 32-63), 8 ch/lane.
// mode 1: ELU -> bf16 h row + layer-2 logits (fp32 dots with va, pre-rounding)
// mode 0: fp32 final output
// ---------------------------------------------------------------------------
__global__ __launch_bounds__(256)
void agg_kernel(const int* __restrict__ row_ptr, const int* __restrict__ col_idx,
                const unsigned short* __restrict__ xWb,
                const float* __restrict__ as_, const float* __restrict__ ad_,
                const float* __restrict__ bias, float* __restrict__ outf,
                unsigned short* __restrict__ hb, const float* __restrict__ va,
                float* __restrict__ as2, float* __restrict__ ad2,
                int N, int mode) {
    const int wv   = (blockIdx.x * 256 + threadIdx.x) >> 6;
    const int lane = threadIdx.x & 63;
    if (wv >= N) return;
    const int i    = wv;
    const int half = lane >> 5;          // edge stream
    const int sl   = lane & 31;
    const int hh   = sl >> 4;            // head of this sublane's channels
    const int cb   = hh * 128 + (sl & 15) * 8;   // 8-channel block base
    const float adi = ad_[i * 2 + hh];

    float acc[8] = {};
    float dn = 0.f;

    const int beg = row_ptr[i];
    const int end = row_ptr[i + 1];

    int k = beg + half;
    int j = (k < end) ? col_idx[k] : 0;
    float asj = as_[j * 2 + hh];
    for (; k < end; k += 2) {
        const int kn = k + 2;
        const int jn = (kn < end) ? col_idx[kn] : 0;
        const float asn = as_[jn * 2 + hh];
        float e = asj + adi;
        e = e > 0.f ? e : NEG * e;
        const float w = expf(e);
        const uint4 q = *reinterpret_cast<const uint4*>(&xWb[(size_t)j * HC + cb]);
        const unsigned qq[4] = {q.x, q.y, q.z, q.w};
        #pragma unroll
        for (int r = 0; r < 4; ++r) {
            const float flo = __uint_as_float(qq[r] << 16);
            const float fhi = __uint_as_float(qq[r] & 0xffff0000u);
            acc[r * 2 + 0] = fmaf(w, flo, acc[r * 2 + 0]);
            acc[r * 2 + 1] = fmaf(w, fhi, acc[r * 2 + 1]);
        }
        dn += w;
        j = jn; asj = asn;
    }

    // merge the two edge streams
    #pragma unroll
    for (int r = 0; r < 8; ++r) acc[r] += __shfl_xor(acc[r], 32);
    dn += __shfl_xor(dn, 32);

    if (lane < 32) {
        // self loop (bf16 row)
        float e = as_[i * 2 + hh] + adi;
        e = e > 0.f ? e : NEG * e;
        const float ws = expf(e);
        const uint4 q = *reinterpret_cast<const uint4*>(&xWb[(size_t)i * HC + cb]);
        const unsigned qq[4] = {q.x, q.y, q.z, q.w};
        #pragma unroll
        for (int r = 0; r < 4; ++r) {
            const float flo = __uint_as_float(qq[r] << 16);
            const float fhi = __uint_as_float(qq[r] & 0xffff0000u);
            acc[r * 2 + 0] = fmaf(ws, flo, acc[r * 2 + 0]);
            acc[r * 2 + 1] = fmaf(ws, fhi, acc[r * 2 + 1]);
        }
        dn += ws;

        const float inv = 1.f / dn;
        const float4 b0 = *reinterpret_cast<const float4*>(&bias[cb]);
        const float4 b1 = *reinterpret_cast<const float4*>(&bias[cb + 4]);
        float o[8];
        o[0] = acc[0] * inv + b0.x; o[1] = acc[1] * inv + b0.y;
        o[2] = acc[2] * inv + b0.z; o[3] = acc[3] * inv + b0.w;
        o[4] = acc[4] * inv + b1.x; o[5] = acc[5] * inv + b1.y;
        o[6] = acc[6] * inv + b1.z; o[7] = acc[7] * inv + b1.w;

        if (mode) {
            // ELU (layer-1 output h)
            #pragma unroll
            for (int r = 0; r < 8; ++r) o[r] = o[r] > 0.f ? o[r] : expm1f(o[r]);
            // bf16 h row (contiguous 16B per lane)
            bfrag8 hv;
            #pragma unroll
            for (int r = 0; r < 8; ++r) hv[r] = (short)f2bf_rne(o[r]);
            *reinterpret_cast<bfrag8*>(&hb[(size_t)i * HC + cb]) = hv;
            // layer-2 logits from fp32 o (pre-rounding): p = sum_c o_c * va[c][*]
            float p0 = 0.f, p1 = 0.f, p2 = 0.f, p3 = 0.f;
            #pragma unroll
            for (int r = 0; r < 8; ++r) {
                const float4 vv = reinterpret_cast<const float4*>(va)[cb + r];
                p0 = fmaf(o[r], vv.x, p0);
                p1 = fmaf(o[r], vv.y, p1);
                p2 = fmaf(o[r], vv.z, p2);
                p3 = fmaf(o[r], vv.w, p3);
            }
            #pragma unroll
            for (int m = 1; m <= 16; m <<= 1) {
                p0 += __shfl_xor(p0, m);
                p1 += __shfl_xor(p1, m);
                p2 += __shfl_xor(p2, m);
                p3 += __shfl_xor(p3, m);
            }
            if (sl == 0) {
                as2[i * 2 + 0] = p0; as2[i * 2 + 1] = p1;
                ad2[i * 2 + 0] = p2; ad2[i * 2 + 1] = p3;
            }
        } else {
            *reinterpret_cast<float4*>(&outf[(size_t)i * HC + cb]) =
                make_float4(o[0], o[1], o[2], o[3]);
            *reinterpret_cast<float4*>(&outf[(size_t)i * HC + cb + 4]) =
                make_float4(o[4], o[5], o[6], o[7]);
        }
    }
}

// ---------------------------------------------------------------------------
extern "C" void kernel_launch(void* const* d_in, const int* in_sizes, int n_in,
                              void* d_out, int out_size, void* d_ws, size_t ws_size,
                              hipStream_t stream) {
    const float* x      = (const float*)d_in[0];
    const int*   ei     = (const int*)d_in[1];
    const float* W1     = (const float*)d_in[2];
    const float* a_src1 = (const float*)d_in[3];
    const float* a_dst1 = (const float*)d_in[4];
    const float* b1     = (const float*)d_in[5];
    const float* W2     = (const float*)d_in[6];
    const float* a_src2 = (const float*)d_in[7];
    const float* a_dst2 = (const float*)d_in[8];
    const float* b2     = (const float*)d_in[9];
    float* out = (float*)d_out;

    const int Nn = in_sizes[0] / 128;   // 50000 nodes
    const int E  = in_sizes[1] / 2;     // 800000 edges
    const int K1 = in_sizes[2] / HC;    // 128
    const int* src = ei;
    const int* dst = ei + E;

    // workspace layout (fp32, int, then 32B-aligned bf16 region)
    float* as1   = (float*)d_ws;                  // Nn*2
    float* ad1   = as1 + (size_t)Nn * 2;
    float* as2   = ad1 + (size_t)Nn * 2;
    float* ad2   = as2 + (size_t)Nn * 2;
    float* va1   = ad2 + (size_t)Nn * 2;          // K1*4
    float* va2   = va1 + (size_t)K1 * 4;          // HC*4
    int*   tmp   = (int*)(va2 + (size_t)HC * 4);  // Nn
    int*   chunk = tmp + Nn;                      // 256
    int*   rowp  = chunk + 256;                   // Nn+1
    int*   curs  = rowp + (Nn + 1);               // Nn
    int*   colx  = curs + Nn;                     // E
    uintptr_t pa = ((uintptr_t)(colx + E) + 31) & ~(uintptr_t)31;
    unsigned short* wt1 = (unsigned short*)pa;           // HC*K1
    unsigned short* wt2 = wt1 + (size_t)HC * K1;         // HC*HC
    unsigned short* xb  = wt2 + (size_t)HC * HC;         // Nn*K1
    unsigned short* xWb = xb  + (size_t)Nn * K1;         // Nn*HC (messages)
    unsigned short* hb  = xWb + (size_t)Nn * HC;         // Nn*HC (h bf16)

    const int nb = (Nn + 255) / 256;

    // ---- tiny prep kernels ----
    wcast_kernel<<<(K1 * HC + 255) / 256, 256, 0, stream>>>(W1, wt1, K1);
    wcast_kernel<<<(HC * HC + 255) / 256, 256, 0, stream>>>(W2, wt2, HC);
    va_kernel<<<(K1 + 3) / 4, 256, 0, stream>>>(W1, a_src1, a_dst1, va1, K1);
    va_kernel<<<(HC + 3) / 4, 256, 0, stream>>>(W2, a_src2, a_dst2, va2, HC);
    xprep_kernel<<<(Nn + 3) / 4, 256, 0, stream>>>(x, va1, xb, as1, ad1, Nn, K1);

    // ---- CSR build (shared by both layers) ----
    hipMemsetAsync(tmp, 0, (size_t)Nn * sizeof(int), stream);
    hist_kernel<<<(E + 255) / 256, 256, 0, stream>>>(dst, tmp, E);
    scan_local_kernel<<<nb, 256, 0, stream>>>(tmp, chunk, Nn);
    scan_chunks_kernel<<<1, 256, 0, stream>>>(chunk, nb);
    add_offsets_kernel<<<nb, 256, 0, stream>>>(tmp, chunk, rowp, curs, Nn, E);
    scatter_kernel<<<(E + 255) / 256, 256, 0, stream>>>(src, dst, curs, colx, E);

    const dim3 ggrid((Nn + 127) / 128, HC / 128);
    const int  agrid = (Nn + 3) / 4;   // one wave per node

    // ---- layer 1 ----
    gemm_msg_kernel<<<ggrid, 256, 0, stream>>>(xb, wt1, xWb, Nn, K1);
    agg_kernel<<<agrid, 256, 0, stream>>>(rowp, colx, xWb, as1, ad1, b1,
                                          (float*)nullptr, hb, va2, as2, ad2, Nn, 1);

    // ---- layer 2 ----
    gemm_msg_kernel<<<ggrid, 256, 0, stream>>>(hb, wt2, xWb, Nn, HC);
    agg_kernel<<<agrid, 256, 0, stream>>>(rowp, colx, xWb, as2, ad2, b2,
                                          out, (unsigned short*)nullptr,
                                          (const float*)nullptr,
                                          (float*)nullptr, (float*)nullptr, Nn, 0);
}

// Round 12
// 333.880 us; speedup vs baseline: 1.0960x; 1.0048x over previous
//
#include <hip/hip_runtime.h>
#include <math.h>

#define HEADS 2
#define CH    128          // per-head channels
#define HC    256          // HEADS*CH
#define NEG   0.2f         // leaky_relu slope

typedef __attribute__((ext_vector_type(8))) _Float16 half8;  // 8 f16 (4 VGPR)
typedef __attribute__((ext_vector_type(4))) float    f32x4;  // MFMA accumulator

// fp32 -> fp16 (RNE) as raw u16
__device__ inline unsigned short f2h(float x) {
    _Float16 h = (_Float16)x;
    unsigned short u;
    __builtin_memcpy(&u, &h, 2);
    return u;
}

// ---------------------------------------------------------------------------
// W cast+transpose: W[K][HC] fp32 -> Wt[HC][K] f16 (k-contiguous)
// ---------------------------------------------------------------------------
__global__ __launch_bounds__(256)
void wcast_kernel(const float* __restrict__ W, unsigned short* __restrict__ Wt, int K) {
    const int idx = blockIdx.x * 256 + threadIdx.x;
    if (idx >= K * HC) return;
    const int k = idx >> 8;          // HC == 256
    const int n = idx & 255;
    Wt[(size_t)n * K + k] = f2h(W[idx]);
}

// ---------------------------------------------------------------------------
// va[k][4] = {src_h0, src_h1, dst_h0, dst_h1} = dot(W[k, head-slice], a_vec)
// ---------------------------------------------------------------------------
__global__ __launch_bounds__(256)
void va_kernel(const float* __restrict__ W, const float* __restrict__ a_src,
               const float* __restrict__ a_dst, float* __restrict__ va, int K) {
    const int k    = (blockIdx.x * 256 + threadIdx.x) >> 6;
    const int lane = threadIdx.x & 63;
    if (k >= K) return;
    const int c0 = lane * 4;
    const float4 w4 = *reinterpret_cast<const float4*>(&W[(size_t)k * HC + c0]);
    const float4 s4 = *reinterpret_cast<const float4*>(&a_src[c0]);
    const float4 d4 = *reinterpret_cast<const float4*>(&a_dst[c0]);
    float ps = w4.x * s4.x + w4.y * s4.y + w4.z * s4.z + w4.w * s4.w;
    float pd = w4.x * d4.x + w4.y * d4.y + w4.z * d4.z + w4.w * d4.w;
    #pragma unroll
    for (int m = 1; m <= 16; m <<= 1) {
        ps += __shfl_xor(ps, m);
        pd += __shfl_xor(pd, m);
    }
    if (lane == 0)  { va[k * 4 + 0] = ps; va[k * 4 + 2] = pd; }
    if (lane == 32) { va[k * 4 + 1] = ps; va[k * 4 + 3] = pd; }
}

// ---------------------------------------------------------------------------
// xprep: per node — f16 cast of x row + exact fp32 logits via va1.
// ---------------------------------------------------------------------------
__global__ __launch_bounds__(256)
void xprep_kernel(const float* __restrict__ x, const float* __restrict__ va,
                  unsigned short* __restrict__ xb, float* __restrict__ as_out,
                  float* __restrict__ ad_out, int N, int K) {
    const int i    = (blockIdx.x * 256 + threadIdx.x) >> 6;
    const int lane = threadIdx.x & 63;
    if (i >= N) return;
    const float2 v = reinterpret_cast<const float2*>(&x[(size_t)i * K])[lane];
    ushort2 bv; bv.x = f2h(v.x); bv.y = f2h(v.y);
    reinterpret_cast<ushort2*>(&xb[(size_t)i * K])[lane] = bv;

    const float4 a0 = reinterpret_cast<const float4*>(va)[lane * 2 + 0];
    const float4 a1 = reinterpret_cast<const float4*>(va)[lane * 2 + 1];
    float p0 = v.x * a0.x + v.y * a1.x;   // src h0
    float p1 = v.x * a0.y + v.y * a1.y;   // src h1
    float p2 = v.x * a0.z + v.y * a1.z;   // dst h0
    float p3 = v.x * a0.w + v.y * a1.w;   // dst h1
    #pragma unroll
    for (int m = 1; m <= 32; m <<= 1) {
        p0 += __shfl_xor(p0, m);
        p1 += __shfl_xor(p1, m);
        p2 += __shfl_xor(p2, m);
        p3 += __shfl_xor(p3, m);
    }
    if (lane == 0) {
        as_out[i * 2 + 0] = p0; as_out[i * 2 + 1] = p1;
        ad_out[i * 2 + 0] = p2; ad_out[i * 2 + 1] = p3;
    }
}

// ---------------------------------------------------------------------------
// Single-pass f16 message GEMM: xWh[M,HC] = f16( Ab[M,K] @ Wt^T )
// tile 128x128, BK=32, 4 waves (2x2), 16 MFMA/k-step.
// ---------------------------------------------------------------------------
__global__ __launch_bounds__(256)
void gemm_msg_kernel(const unsigned short* __restrict__ Ab,
                     const unsigned short* __restrict__ Wt,
                     unsigned short* __restrict__ xWh, int M, int K) {
    __shared__ unsigned short Ah[128][40];
    __shared__ unsigned short Bh[128][40];

    const int t    = threadIdx.x;
    const int row0 = blockIdx.x * 128;
    const int col0 = blockIdx.y * 128;
    const int lane = t & 63;
    const int wid  = t >> 6;
    const int wr   = wid >> 1;
    const int wc   = wid & 1;

    f32x4 acc[4][4] = {};

    const int arow = t & 127;        // staging row / col
    const int aseg = (t >> 7) * 16;  // k segment 0 or 16

    for (int kk = 0; kk < K; kk += 32) {
        {
            const int gr = row0 + arow;
            half8 v0 = {0,0,0,0,0,0,0,0}, v1 = {0,0,0,0,0,0,0,0};
            if (gr < M) {
                v0 = *reinterpret_cast<const half8*>(&Ab[(size_t)gr * K + kk + aseg]);
                v1 = *reinterpret_cast<const half8*>(&Ab[(size_t)gr * K + kk + aseg + 8]);
            }
            *reinterpret_cast<half8*>(&Ah[arow][aseg])     = v0;
            *reinterpret_cast<half8*>(&Ah[arow][aseg + 8]) = v1;
            const half8 w0 = *reinterpret_cast<const half8*>(
                &Wt[(size_t)(col0 + arow) * K + kk + aseg]);
            const half8 w1 = *reinterpret_cast<const half8*>(
                &Wt[(size_t)(col0 + arow) * K + kk + aseg + 8]);
            *reinterpret_cast<half8*>(&Bh[arow][aseg])     = w0;
            *reinterpret_cast<half8*>(&Bh[arow][aseg + 8]) = w1;
        }
        __syncthreads();

        half8 ah[4], bh[4];
        const int ko = (lane >> 4) * 8;
        #pragma unroll
        for (int m = 0; m < 4; ++m)
            ah[m] = *reinterpret_cast<const half8*>(&Ah[wr * 64 + m * 16 + (lane & 15)][ko]);
        #pragma unroll
        for (int n = 0; n < 4; ++n)
            bh[n] = *reinterpret_cast<const half8*>(&Bh[wc * 64 + n * 16 + (lane & 15)][ko]);

        #pragma unroll
        for (int m = 0; m < 4; ++m)
            #pragma unroll
            for (int n = 0; n < 4; ++n)
                acc[m][n] = __builtin_amdgcn_mfma_f32_16x16x32_f16(ah[m], bh[n], acc[m][n], 0, 0, 0);
        __syncthreads();
    }

    // epilogue: f16 stores (C/D layout col=lane&15, row=(lane>>4)*4+reg)
    #pragma unroll
    for (int m = 0; m < 4; ++m) {
        #pragma unroll
        for (int reg = 0; reg < 4; ++reg) {
            const int gr = row0 + wr * 64 + m * 16 + (lane >> 4) * 4 + reg;
            if (gr < M) {
                unsigned short* rp = &xWh[(size_t)gr * HC + col0];
                #pragma unroll
                for (int n = 0; n < 4; ++n)
                    rp[wc * 64 + n * 16 + (lane & 15)] = f2h(acc[m][n][reg]);
            }
        }
    }
}

// ---------------------------------------------------------------------------
// CSR build: histogram -> 2-level exclusive scan -> scatter (by destination)
// ---------------------------------------------------------------------------
__global__ __launch_bounds__(256)
void hist_kernel(const int* __restrict__ dst, int* __restrict__ counts, int E) {
    const int e = blockIdx.x * 256 + threadIdx.x;
    if (e < E) atomicAdd(&counts[dst[e]], 1);
}

__global__ __launch_bounds__(256)
void scan_local_kernel(int* __restrict__ data, int* __restrict__ chunk_sum, int N) {
    __shared__ int s[256];
    const int t   = threadIdx.x;
    const int idx = blockIdx.x * 256 + t;
    const int v   = (idx < N) ? data[idx] : 0;
    s[t] = v;
    __syncthreads();
    #pragma unroll
    for (int off = 1; off < 256; off <<= 1) {
        int x = (t >= off) ? s[t - off] : 0;
        __syncthreads();
        s[t] += x;
        __syncthreads();
    }
    if (idx < N) data[idx] = s[t] - v;        // exclusive
    if (t == 255) chunk_sum[blockIdx.x] = s[255];
}

__global__ __launch_bounds__(256)
void scan_chunks_kernel(int* __restrict__ chunk, int nb) {
    __shared__ int s[256];
    const int t = threadIdx.x;
    const int v = (t < nb) ? chunk[t] : 0;
    s[t] = v;
    __syncthreads();
    #pragma unroll
    for (int off = 1; off < 256; off <<= 1) {
        int x = (t >= off) ? s[t - off] : 0;
        __syncthreads();
        s[t] += x;
        __syncthreads();
    }
    if (t < nb) chunk[t] = s[t] - v;
}

__global__ __launch_bounds__(256)
void add_offsets_kernel(const int* __restrict__ excl, const int* __restrict__ chunk_excl,
                        int* __restrict__ row_ptr, int* __restrict__ cursor,
                        int N, int E) {
    const int idx = blockIdx.x * 256 + threadIdx.x;
    if (idx < N) {
        const int rp = excl[idx] + chunk_excl[idx >> 8];
        row_ptr[idx] = rp;
        cursor[idx]  = rp;
    }
    if (idx == 0) row_ptr[N] = E;
}

__global__ __launch_bounds__(256)
void scatter_kernel(const int* __restrict__ src, const int* __restrict__ dst,
                    int* __restrict__ cursor, int* __restrict__ col_idx, int E) {
    const int e = blockIdx.x * 256 + threadIdx.x;
    if (e < E) {
        const int pos = atomicAdd(&cursor[dst[e]], 1);
        col_idx[pos] = src[e];
    }
}

// ---------------------------------------------------------------------------
// gather aggregation + fused epilogue: one wave per target node.
// f16 messages (v_fma_mix unpack-free FMA); 2 edge streams; 2-deep pipeline.
// mode 1: ELU -> f16 h row + layer-2 logits (fp32, pre-rounding)
// mode 0: fp32 final output
// ---------------------------------------------------------------------------
__global__ __launch_bounds__(256)
void agg_kernel(const int* __restrict__ row_ptr, const int* __restrict__ col_idx,
                const unsigned short* __restrict__ xWh,
                const float* __restrict__ as_, const float* __restrict__ ad_,
                const float* __restrict__ bias, float* __restrict__ outf,
                unsigned short* __restrict__ hb, const float* __restrict__ va,
                float* __restrict__ as2, float* __restrict__ ad2,
                int N, int mode) {
    const int wv   = (blockIdx.x * 256 + threadIdx.x) >> 6;
    const int lane = threadIdx.x & 63;
    if (wv >= N) return;
    const int i    = wv;
    const int half = lane >> 5;          // edge stream
    const int sl   = lane & 31;
    const int hh   = sl >> 4;            // head of this sublane's channels
    const int cb   = hh * 128 + (sl & 15) * 8;   // 8-channel block base
    const float adi = ad_[i * 2 + hh];

    float acc[8] = {};
    float dn = 0.f;

    const int beg = row_ptr[i];
    const int end = row_ptr[i + 1];

    int k = beg + half;
    float asj = 0.f;
    half8 hv = {0,0,0,0,0,0,0,0};
    if (k < end) {
        const int j0 = col_idx[k];
        asj = as_[j0 * 2 + hh];
        hv  = *reinterpret_cast<const half8*>(&xWh[(size_t)j0 * HC + cb]);
    }
    for (; k < end; k += 2) {
        const int kn = k + 2;
        // issue next row load before current compute (hide gather latency)
        int jn = 0;
        float asn = 0.f;
        half8 hn = {0,0,0,0,0,0,0,0};
        if (kn < end) {
            jn  = col_idx[kn];
            asn = as_[jn * 2 + hh];
            hn  = *reinterpret_cast<const half8*>(&xWh[(size_t)jn * HC + cb]);
        }
        float e = asj + adi;
        e = e > 0.f ? e : NEG * e;
        const float w = __expf(e);
        #pragma unroll
        for (int r = 0; r < 8; ++r)
            acc[r] = fmaf(w, (float)hv[r], acc[r]);   // v_fma_mix_f32
        dn += w;
        hv = hn; asj = asn;
    }

    // merge the two edge streams
    #pragma unroll
    for (int r = 0; r < 8; ++r) acc[r] += __shfl_xor(acc[r], 32);
    dn += __shfl_xor(dn, 32);

    if (lane < 32) {
        // self loop (f16 row)
        float e = as_[i * 2 + hh] + adi;
        e = e > 0.f ? e : NEG * e;
        const float ws = __expf(e);
        const half8 sv = *reinterpret_cast<const half8*>(&xWh[(size_t)i * HC + cb]);
        #pragma unroll
        for (int r = 0; r < 8; ++r)
            acc[r] = fmaf(ws, (float)sv[r], acc[r]);
        dn += ws;

        const float inv = 1.f / dn;
        const float4 b0 = *reinterpret_cast<const float4*>(&bias[cb]);
        const float4 b1 = *reinterpret_cast<const float4*>(&bias[cb + 4]);
        float o[8];
        o[0] = acc[0] * inv + b0.x; o[1] = acc[1] * inv + b0.y;
        o[2] = acc[2] * inv + b0.z; o[3] = acc[3] * inv + b0.w;
        o[4] = acc[4] * inv + b1.x; o[5] = acc[5] * inv + b1.y;
        o[6] = acc[6] * inv + b1.z; o[7] = acc[7] * inv + b1.w;

        if (mode) {
            // ELU (layer-1 output h)
            #pragma unroll
            for (int r = 0; r < 8; ++r) o[r] = o[r] > 0.f ? o[r] : expm1f(o[r]);
            // f16 h row (contiguous 16B per lane)
            half8 hvo;
            #pragma unroll
            for (int r = 0; r < 8; ++r) hvo[r] = (_Float16)o[r];
            *reinterpret_cast<half8*>(&hb[(size_t)i * HC + cb]) = hvo;
            // layer-2 logits from fp32 o (pre-rounding)
            float p0 = 0.f, p1 = 0.f, p2 = 0.f, p3 = 0.f;
            #pragma unroll
            for (int r = 0; r < 8; ++r) {
                const float4 vv = reinterpret_cast<const float4*>(va)[cb + r];
                p0 = fmaf(o[r], vv.x, p0);
                p1 = fmaf(o[r], vv.y, p1);
                p2 = fmaf(o[r], vv.z, p2);
                p3 = fmaf(o[r], vv.w, p3);
            }
            #pragma unroll
            for (int m = 1; m <= 16; m <<= 1) {
                p0 += __shfl_xor(p0, m);
                p1 += __shfl_xor(p1, m);
                p2 += __shfl_xor(p2, m);
                p3 += __shfl_xor(p3, m);
            }
            if (sl == 0) {
                as2[i * 2 + 0] = p0; as2[i * 2 + 1] = p1;
                ad2[i * 2 + 0] = p2; ad2[i * 2 + 1] = p3;
            }
        } else {
            *reinterpret_cast<float4*>(&outf[(size_t)i * HC + cb]) =
                make_float4(o[0], o[1], o[2], o[3]);
            *reinterpret_cast<float4*>(&outf[(size_t)i * HC + cb + 4]) =
                make_float4(o[4], o[5], o[6], o[7]);
        }
    }
}

// ---------------------------------------------------------------------------
extern "C" void kernel_launch(void* const* d_in, const int* in_sizes, int n_in,
                              void* d_out, int out_size, void* d_ws, size_t ws_size,
                              hipStream_t stream) {
    const float* x      = (const float*)d_in[0];
    const int*   ei     = (const int*)d_in[1];
    const float* W1     = (const float*)d_in[2];
    const float* a_src1 = (const float*)d_in[3];
    const float* a_dst1 = (const float*)d_in[4];
    const float* b1     = (const float*)d_in[5];
    const float* W2     = (const float*)d_in[6];
    const float* a_src2 = (const float*)d_in[7];
    const float* a_dst2 = (const float*)d_in[8];
    const float* b2     = (const float*)d_in[9];
    float* out = (float*)d_out;

    const int Nn = in_sizes[0] / 128;   // 50000 nodes
    const int E  = in_sizes[1] / 2;     // 800000 edges
    const int K1 = in_sizes[2] / HC;    // 128
    const int* src = ei;
    const int* dst = ei + E;

    // workspace layout (fp32, int, then 32B-aligned f16 region)
    float* as1   = (float*)d_ws;                  // Nn*2
    float* ad1   = as1 + (size_t)Nn * 2;
    float* as2   = ad1 + (size_t)Nn * 2;
    float* ad2   = as2 + (size_t)Nn * 2;
    float* va1   = ad2 + (size_t)Nn * 2;          // K1*4
    float* va2   = va1 + (size_t)K1 * 4;          // HC*4
    int*   tmp   = (int*)(va2 + (size_t)HC * 4);  // Nn
    int*   chunk = tmp + Nn;                      // 256
    int*   rowp  = chunk + 256;                   // Nn+1
    int*   curs  = rowp + (Nn + 1);               // Nn
    int*   colx  = curs + Nn;                     // E
    uintptr_t pa = ((uintptr_t)(colx + E) + 31) & ~(uintptr_t)31;
    unsigned short* wt1 = (unsigned short*)pa;           // HC*K1
    unsigned short* wt2 = wt1 + (size_t)HC * K1;         // HC*HC
    unsigned short* xb  = wt2 + (size_t)HC * HC;         // Nn*K1
    unsigned short* xWh = xb  + (size_t)Nn * K1;         // Nn*HC (messages)
    unsigned short* hb  = xWh + (size_t)Nn * HC;         // Nn*HC (h f16)

    const int nb = (Nn + 255) / 256;

    // ---- tiny prep kernels ----
    wcast_kernel<<<(K1 * HC + 255) / 256, 256, 0, stream>>>(W1, wt1, K1);
    wcast_kernel<<<(HC * HC + 255) / 256, 256, 0, stream>>>(W2, wt2, HC);
    va_kernel<<<(K1 + 3) / 4, 256, 0, stream>>>(W1, a_src1, a_dst1, va1, K1);
    va_kernel<<<(HC + 3) / 4, 256, 0, stream>>>(W2, a_src2, a_dst2, va2, HC);
    xprep_kernel<<<(Nn + 3) / 4, 256, 0, stream>>>(x, va1, xb, as1, ad1, Nn, K1);

    // ---- CSR build (shared by both layers) ----
    hipMemsetAsync(tmp, 0, (size_t)Nn * sizeof(int), stream);
    hist_kernel<<<(E + 255) / 256, 256, 0, stream>>>(dst, tmp, E);
    scan_local_kernel<<<nb, 256, 0, stream>>>(tmp, chunk, Nn);
    scan_chunks_kernel<<<1, 256, 0, stream>>>(chunk, nb);
    add_offsets_kernel<<<nb, 256, 0, stream>>>(tmp, chunk, rowp, curs, Nn, E);
    scatter_kernel<<<(E + 255) / 256, 256, 0, stream>>>(src, dst, curs, colx, E);

    const dim3 ggrid((Nn + 127) / 128, HC / 128);
    const int  agrid = (Nn + 3) / 4;   // one wave per node

    // ---- layer 1 ----
    gemm_msg_kernel<<<ggrid, 256, 0, stream>>>(xb, wt1, xWh, Nn, K1);
    agg_kernel<<<agrid, 256, 0, stream>>>(rowp, colx, xWh, as1, ad1, b1,
                                          (float*)nullptr, hb, va2, as2, ad2, Nn, 1);

    // ---- layer 2 ----
    gemm_msg_kernel<<<ggrid, 256, 0, stream>>>(hb, wt2, xWh, Nn, HC);
    agg_kernel<<<agrid, 256, 0, stream>>>(rowp, colx, xWh, as2, ad2, b2,
                                          out, (unsigned short*)nullptr,
                                          (const float*)nullptr,
                                          (float*)nullptr, (float*)nullptr, Nn, 0);
}